// Round 1
// baseline (246.498 us; speedup 1.0000x reference)
//
#include <hip/hip_runtime.h>
#include <math.h>

#define BB 4
#define CC 64
#define NN 4096
#define IND 8
#define HF 32
#define MT 256
#define WAVES 8
#define THREADS 512

// Kernel 1: channel projections f,g,hv from x (1x1 convs).
__global__ __launch_bounds__(64) void proj_kernel(
    const float* __restrict__ x,
    const float* __restrict__ Wf, const float* __restrict__ bf,
    const float* __restrict__ Wg, const float* __restrict__ bg,
    const float* __restrict__ Wh, const float* __restrict__ bh,
    float* __restrict__ fT, float* __restrict__ g, float* __restrict__ hv)
{
    __shared__ float swf[IND*CC], swg[IND*CC], swh[HF*CC];
    int tid = threadIdx.x;
    for (int i = tid; i < IND*CC; i += 64) { swf[i] = Wf[i]; swg[i] = Wg[i]; }
    for (int i = tid; i < HF*CC; i += 64) swh[i] = Wh[i];
    __syncthreads();

    int idx = blockIdx.x * 64 + tid;          // 0 .. B*N-1
    int b = idx >> 12;                        // N = 4096
    int n = idx & (NN - 1);
    const float* xp = x + (size_t)b * CC * NN + n;

    float fa[IND], ga[IND], ha[HF];
    #pragma unroll
    for (int o = 0; o < IND; o++) { fa[o] = bf[o]; ga[o] = bg[o]; }
    #pragma unroll
    for (int h = 0; h < HF; h++) ha[h] = bh[h];

    for (int c = 0; c < CC; c++) {
        float xv = xp[(size_t)c * NN];
        #pragma unroll
        for (int o = 0; o < IND; o++) {
            fa[o] += swf[o*CC + c] * xv;
            ga[o] += swg[o*CC + c] * xv;
        }
        #pragma unroll
        for (int h = 0; h < HF; h++) ha[h] += swh[h*CC + c] * xv;
    }

    size_t base8 = (size_t)b * IND * NN + n;
    #pragma unroll
    for (int o = 0; o < IND; o++) {
        fT[base8 + (size_t)o*NN] = fa[o];
        g [base8 + (size_t)o*NN] = ga[o];
    }
    size_t base32 = (size_t)b * HF * NN + n;
    #pragma unroll
    for (int h = 0; h < HF; h++) hv[base32 + (size_t)h*NN] = ha[h];
}

// Kernel 2: flash-style attention (no max shift; f32 exp is safe here) +
// fused Wv projection, gamma scale, residual add.
// Grid: 256 WGs = B * (N/64). Block: 512 threads = 8 waves.
// Each wave: lane = query (64 queries per WG), covers a disjoint 1/8 of each
// staged 256-column m-tile. LDS reads are wave-uniform -> broadcast (free).
__global__ __launch_bounds__(THREADS) void attn_kernel(
    const float* __restrict__ fT, const float* __restrict__ g,
    const float* __restrict__ hv,
    const float* __restrict__ Wv, const float* __restrict__ bv,
    const float* __restrict__ gamma,
    const float* __restrict__ x, float* __restrict__ out)
{
    __shared__ float sg[IND][MT];
    __shared__ float sh[HF][MT];
    __shared__ float so[64][HF + 2];   // [q][0..31]=acc, [q][32]=L (pad to 34)

    int tid  = threadIdx.x;
    int wave = tid >> 6;
    int lane = tid & 63;
    int b  = blockIdx.x >> 6;              // 64 query-tiles per batch
    int n0 = (blockIdx.x & 63) * 64;
    int n  = n0 + lane;                    // this lane's query row

    for (int i = tid; i < 64*(HF+2); i += THREADS) ((float*)so)[i] = 0.f;

    // per-query f vector
    float fq[IND];
    size_t fbase = (size_t)b * IND * NN + n;
    #pragma unroll
    for (int o = 0; o < IND; o++) fq[o] = fT[fbase + (size_t)o*NN];

    float acc[HF];
    #pragma unroll
    for (int h = 0; h < HF; h++) acc[h] = 0.f;
    float L = 0.f;

    const float* gb = g  + (size_t)b * IND * NN;
    const float* hb = hv + (size_t)b * HF  * NN;

    __syncthreads();   // so[] zeroed

    for (int mt = 0; mt < NN; mt += MT) {
        // stage g-tile [8][MT] and hv-tile [32][MT] (coalesced)
        for (int i = tid; i < IND*MT; i += THREADS) {
            int o = i >> 8, j = i & (MT-1);
            sg[o][j] = gb[(size_t)o*NN + mt + j];
        }
        for (int i = tid; i < HF*MT; i += THREADS) {
            int h2 = i >> 8, j = i & (MT-1);
            sh[h2][j] = hb[(size_t)h2*NN + mt + j];
        }
        __syncthreads();

        int m0 = wave * (MT / WAVES);
        #pragma unroll 4
        for (int i = 0; i < MT / WAVES; i++) {
            int m = m0 + i;
            float s = 0.f;
            #pragma unroll
            for (int o = 0; o < IND; o++) s += fq[o] * sg[o][m];
            float e = __expf(s);
            L += e;
            #pragma unroll
            for (int h = 0; h < HF; h++) acc[h] += e * sh[h][m];
        }
        __syncthreads();
    }

    // combine wave partials (no max shift -> simple sums)
    #pragma unroll
    for (int h = 0; h < HF; h++) atomicAdd(&so[lane][h], acc[h]);
    atomicAdd(&so[lane][HF], L);
    __syncthreads();

    // epilogue: 512 threads = 64 queries x 8 channel-blocks of 8
    int q  = tid & 63;
    int cb = tid >> 6;
    float rL = 1.f / so[q][HF];
    float o_[HF];
    #pragma unroll
    for (int h = 0; h < HF; h++) o_[h] = so[q][h] * rL;
    float gm = gamma[0];
    size_t obase = (size_t)b * CC * NN + n0 + q;
    for (int c = cb*8; c < cb*8 + 8; c++) {
        float v = bv[c];
        #pragma unroll
        for (int h = 0; h < HF; h++) v += Wv[c*HF + h] * o_[h];
        size_t a = obase + (size_t)c * NN;
        out[a] = gm * v + x[a];
    }
}

extern "C" void kernel_launch(void* const* d_in, const int* in_sizes, int n_in,
                              void* d_out, int out_size, void* d_ws, size_t ws_size,
                              hipStream_t stream) {
    const float* x     = (const float*)d_in[0];
    const float* Wf    = (const float*)d_in[1];
    const float* bf    = (const float*)d_in[2];
    const float* Wg    = (const float*)d_in[3];
    const float* bg    = (const float*)d_in[4];
    const float* Wh    = (const float*)d_in[5];
    const float* bh    = (const float*)d_in[6];
    const float* Wv    = (const float*)d_in[7];
    const float* bv    = (const float*)d_in[8];
    const float* gamma = (const float*)d_in[9];
    float* out = (float*)d_out;

    float* ws = (float*)d_ws;
    float* fT = ws;                              // B*8*N
    float* g  = ws + (size_t)BB*IND*NN;          // B*8*N
    float* hv = ws + (size_t)2*BB*IND*NN;        // B*32*N

    proj_kernel<<<(BB*NN)/64, 64, 0, stream>>>(x, Wf, bf, Wg, bg, Wh, bh, fT, g, hv);
    attn_kernel<<<BB*(NN/64), THREADS, 0, stream>>>(fT, g, hv, Wv, bv, gamma, x, out);
}

// Round 2
// 201.099 us; speedup vs baseline: 1.2258x; 1.2258x over previous
//
#include <hip/hip_runtime.h>
#include <math.h>

#define BB 4
#define CC 64
#define NN 4096
#define IND 8
#define HF 32
#define MT 256
#define WAVES 8
#define THREADS 512

// Kernel 1: channel projections f,g,hv from x (1x1 convs).
// Outputs: fT [B][8][N]  (per-o coalesced reads by attn lanes)
//          gT [B][N][8]  (transposed: per-m contiguous -> float4 LDS tiles)
//          hvT[B][N][32] (transposed: per-m contiguous -> float4 LDS tiles)
__global__ __launch_bounds__(64) void proj_kernel(
    const float* __restrict__ x,
    const float* __restrict__ Wf, const float* __restrict__ bf,
    const float* __restrict__ Wg, const float* __restrict__ bg,
    const float* __restrict__ Wh, const float* __restrict__ bh,
    float* __restrict__ fT, float* __restrict__ gT, float* __restrict__ hvT)
{
    __shared__ float swf[IND*CC], swg[IND*CC], swh[HF*CC];
    int tid = threadIdx.x;
    for (int i = tid; i < IND*CC; i += 64) { swf[i] = Wf[i]; swg[i] = Wg[i]; }
    for (int i = tid; i < HF*CC; i += 64) swh[i] = Wh[i];
    __syncthreads();

    int idx = blockIdx.x * 64 + tid;          // 0 .. B*N-1
    int b = idx >> 12;                        // N = 4096
    int n = idx & (NN - 1);
    const float* xp = x + (size_t)b * CC * NN + n;

    float fa[IND], ga[IND], ha[HF];
    #pragma unroll
    for (int o = 0; o < IND; o++) { fa[o] = bf[o]; ga[o] = bg[o]; }
    #pragma unroll
    for (int h = 0; h < HF; h++) ha[h] = bh[h];

    for (int c = 0; c < CC; c++) {
        float xv = xp[(size_t)c * NN];
        #pragma unroll
        for (int o = 0; o < IND; o++) {
            fa[o] += swf[o*CC + c] * xv;
            ga[o] += swg[o*CC + c] * xv;
        }
        #pragma unroll
        for (int h = 0; h < HF; h++) ha[h] += swh[h*CC + c] * xv;
    }

    size_t base8 = (size_t)b * IND * NN + n;
    #pragma unroll
    for (int o = 0; o < IND; o++) fT[base8 + (size_t)o*NN] = fa[o];

    float* gp = gT + ((size_t)b * NN + n) * IND;
    #pragma unroll
    for (int o = 0; o < IND; o++) gp[o] = ga[o];

    float* hp = hvT + ((size_t)b * NN + n) * HF;
    #pragma unroll
    for (int h = 0; h < HF; h++) hp[h] = ha[h];
}

// Kernel 2: flash-style attention (no max shift; f32 exp is safe: |s| <~ 12)
// + fused Wv projection, gamma scale, residual add.
// Grid: 256 WGs = B * (N/64). Block: 512 threads = 8 waves.
// lane = query; waves split each staged 256-m tile 8 ways.
// All inner-loop LDS reads are wave-uniform float4 broadcasts (conflict-free,
// 10 ds_read_b128 per m instead of 40 ds_read_b32).
__global__ __launch_bounds__(THREADS) void attn_kernel(
    const float* __restrict__ fT, const float* __restrict__ gT,
    const float* __restrict__ hvT,
    const float* __restrict__ Wv, const float* __restrict__ bv,
    const float* __restrict__ gamma,
    const float* __restrict__ x, float* __restrict__ out)
{
    __shared__ float4 sg4[MT*2];       // gT tile  [MT][8]  = MT*2 float4 (8 KB)
    __shared__ float4 sh4[MT*8];       // hvT tile [MT][32] = MT*8 float4 (32 KB)
    __shared__ float so[64][HF + 2];   // [q][0..31]=acc, [q][32]=L (pad to 34)

    int tid  = threadIdx.x;
    int wave = tid >> 6;
    int lane = tid & 63;
    int b  = blockIdx.x >> 6;              // 64 query-tiles per batch
    int n0 = (blockIdx.x & 63) * 64;
    int n  = n0 + lane;                    // this lane's query row

    for (int i = tid; i < 64*(HF+2); i += THREADS) ((float*)so)[i] = 0.f;

    // per-query f vector (two float4s)
    const float* fb = fT + (size_t)b * IND * NN + n;
    float4 fq0 = make_float4(fb[0],          fb[(size_t)NN],   fb[(size_t)2*NN], fb[(size_t)3*NN]);
    float4 fq1 = make_float4(fb[(size_t)4*NN], fb[(size_t)5*NN], fb[(size_t)6*NN], fb[(size_t)7*NN]);

    float4 acc[8];
    #pragma unroll
    for (int k = 0; k < 8; k++) acc[k] = make_float4(0.f, 0.f, 0.f, 0.f);
    float L = 0.f;

    const float4* gTb = (const float4*)(gT  + (size_t)b * NN * IND);  // 2 float4 per m
    const float4* hTb = (const float4*)(hvT + (size_t)b * NN * HF);   // 8 float4 per m

    __syncthreads();   // so[] zeroed

    for (int mt = 0; mt < NN; mt += MT) {
        // stage tiles (contiguous float4 copies, fully coalesced)
        {
            const float4* src = gTb + (size_t)mt * 2;
            for (int i = tid; i < MT*2; i += THREADS) sg4[i] = src[i];
            const float4* src2 = hTb + (size_t)mt * 8;
            for (int i = tid; i < MT*8; i += THREADS) sh4[i] = src2[i];
        }
        __syncthreads();

        int m0 = wave * (MT / WAVES);
        #pragma unroll 2
        for (int i = 0; i < MT / WAVES; i++) {
            int m = m0 + i;
            float4 ga0 = sg4[m*2 + 0];
            float4 ga1 = sg4[m*2 + 1];
            float s = fq0.x*ga0.x + fq0.y*ga0.y + fq0.z*ga0.z + fq0.w*ga0.w
                    + fq1.x*ga1.x + fq1.y*ga1.y + fq1.z*ga1.z + fq1.w*ga1.w;
            float e = __expf(s);
            L += e;
            #pragma unroll
            for (int k = 0; k < 8; k++) {
                float4 hv4 = sh4[m*8 + k];
                acc[k].x += e * hv4.x;
                acc[k].y += e * hv4.y;
                acc[k].z += e * hv4.z;
                acc[k].w += e * hv4.w;
            }
        }
        __syncthreads();
    }

    // combine wave partials (no max shift -> simple sums)
    #pragma unroll
    for (int k = 0; k < 8; k++) {
        atomicAdd(&so[lane][4*k + 0], acc[k].x);
        atomicAdd(&so[lane][4*k + 1], acc[k].y);
        atomicAdd(&so[lane][4*k + 2], acc[k].z);
        atomicAdd(&so[lane][4*k + 3], acc[k].w);
    }
    atomicAdd(&so[lane][HF], L);
    __syncthreads();

    // epilogue: 512 threads = 64 queries x 8 channel-blocks of 8
    int q  = tid & 63;
    int cb = tid >> 6;
    float rL = 1.f / so[q][HF];
    float o_[HF];
    #pragma unroll
    for (int h = 0; h < HF; h++) o_[h] = so[q][h] * rL;
    float gm = gamma[0];
    size_t obase = (size_t)b * CC * NN + n0 + q;
    for (int c = cb*8; c < cb*8 + 8; c++) {
        float v = bv[c];
        #pragma unroll
        for (int h = 0; h < HF; h++) v += Wv[c*HF + h] * o_[h];
        size_t a = obase + (size_t)c * NN;
        out[a] = gm * v + x[a];
    }
}

extern "C" void kernel_launch(void* const* d_in, const int* in_sizes, int n_in,
                              void* d_out, int out_size, void* d_ws, size_t ws_size,
                              hipStream_t stream) {
    const float* x     = (const float*)d_in[0];
    const float* Wf    = (const float*)d_in[1];
    const float* bf    = (const float*)d_in[2];
    const float* Wg    = (const float*)d_in[3];
    const float* bg    = (const float*)d_in[4];
    const float* Wh    = (const float*)d_in[5];
    const float* bh    = (const float*)d_in[6];
    const float* Wv    = (const float*)d_in[7];
    const float* bv    = (const float*)d_in[8];
    const float* gamma = (const float*)d_in[9];
    float* out = (float*)d_out;

    float* ws  = (float*)d_ws;
    float* fT  = ws;                               // B*8*N
    float* gT  = ws + (size_t)BB*IND*NN;           // B*N*8
    float* hvT = ws + (size_t)2*BB*IND*NN;         // B*N*32

    proj_kernel<<<(BB*NN)/64, 64, 0, stream>>>(x, Wf, bf, Wg, bg, Wh, bh, fT, gT, hvT);
    attn_kernel<<<BB*(NN/64), THREADS, 0, stream>>>(fT, gT, hvT, Wv, bv, gamma, x, out);
}

// Round 3
// 68.926 us; speedup vs baseline: 3.5763x; 2.9176x over previous
//
#include <hip/hip_runtime.h>
#include <math.h>

#define BB 4
#define CC 64
#define NN 4096
#define IND 8
#define HF 32
#define NH 48          // V' rows: 32 outputs + 1 ones (L) + 15 zeros
#define THREADS 512
#define WAVES 8
#define MBLK 32        // m's per inner block
#define MCHUNK (NN/WAVES)   // 512 m's per wave
#define NBLK (MCHUNK/MBLK)  // 16 blocks
#define LROW 40        // padded LDS row in ushorts (80 B -> 2-way max conflicts)

typedef __attribute__((ext_vector_type(8))) short bf16x8;
typedef __attribute__((ext_vector_type(4))) float f32x4;

static __device__ __forceinline__ unsigned short f2bf(float x) {
    unsigned int u = __float_as_uint(x);
    u = (u + 0x7FFFu + ((u >> 16) & 1u)) >> 16;   // RNE
    return (unsigned short)u;
}
static __device__ __forceinline__ float bf2f(unsigned short h) {
    return __uint_as_float(((unsigned int)h) << 16);
}

// Kernel 1: 1x1-conv projections -> packed bf16 workspaces.
// fpk [B][N][16]: [fh(8), fl(8)]          (Q hi/lo split)
// gpk [B][N][32]: [gh, gh, gl, gl]        (K packed for the split-QK trick)
// vpkT[B][48][N]: row h holds bf16(hv[h][m]) at PERMUTED column
//                 pos(m) = (m&~31) | 2*(m&15) | ((m>>4)&1)  (matches P coding)
//                 row 32 = 1.0 (L accumulator), rows 33..47 = 0.
__global__ __launch_bounds__(64) void proj_kernel(
    const float* __restrict__ x,
    const float* __restrict__ Wf, const float* __restrict__ bf,
    const float* __restrict__ Wg, const float* __restrict__ bg,
    const float* __restrict__ Wh, const float* __restrict__ bh,
    unsigned short* __restrict__ fpk,
    unsigned short* __restrict__ gpk,
    unsigned short* __restrict__ vpkT)
{
    __shared__ float swf[IND*CC], swg[IND*CC], swh[HF*CC];
    int tid = threadIdx.x;
    for (int i = tid; i < IND*CC; i += 64) { swf[i] = Wf[i]; swg[i] = Wg[i]; }
    for (int i = tid; i < HF*CC; i += 64) swh[i] = Wh[i];
    __syncthreads();

    int idx = blockIdx.x * 64 + tid;
    int b = idx >> 12;
    int n = idx & (NN - 1);
    const float* xp = x + (size_t)b * CC * NN + n;

    float fa[IND], ga[IND], ha[HF];
    #pragma unroll
    for (int o = 0; o < IND; o++) { fa[o] = bf[o]; ga[o] = bg[o]; }
    #pragma unroll
    for (int h = 0; h < HF; h++) ha[h] = bh[h];

    for (int c = 0; c < CC; c++) {
        float xv = xp[(size_t)c * NN];
        #pragma unroll
        for (int o = 0; o < IND; o++) {
            fa[o] += swf[o*CC + c] * xv;
            ga[o] += swg[o*CC + c] * xv;
        }
        #pragma unroll
        for (int h = 0; h < HF; h++) ha[h] += swh[h*CC + c] * xv;
    }

    size_t base = (size_t)b * NN + n;
    unsigned short* fp = fpk + base * 16;
    #pragma unroll
    for (int o = 0; o < IND; o++) {
        unsigned short hi = f2bf(fa[o]);
        unsigned short lo = f2bf(fa[o] - bf2f(hi));
        fp[o] = hi; fp[8 + o] = lo;
    }
    unsigned short* gp = gpk + base * 32;
    #pragma unroll
    for (int o = 0; o < IND; o++) {
        unsigned short hi = f2bf(ga[o]);
        unsigned short lo = f2bf(ga[o] - bf2f(hi));
        gp[o] = hi; gp[8 + o] = hi; gp[16 + o] = lo; gp[24 + o] = lo;
    }
    int pos = (n & ~31) | ((n & 15) << 1) | ((n >> 4) & 1);
    unsigned short* vp = vpkT + (size_t)b * NH * NN + pos;
    #pragma unroll
    for (int h = 0; h < HF; h++) vp[(size_t)h * NN] = f2bf(ha[h]);
    vp[(size_t)32 * NN] = 0x3F80;          // 1.0 bf16 -> L column
    #pragma unroll
    for (int h = 33; h < NH; h++) vp[(size_t)h * NN] = 0;
}

// Kernel 2: MFMA flash attention + fused Wv/gamma/residual epilogue.
// 256 WGs = B * (N/64). 8 waves; each wave owns all 64 queries of the tile
// and a private 512-m strip with private LDS buffers -> no main-loop barriers.
__global__ __launch_bounds__(THREADS) void attn_kernel(
    const unsigned short* __restrict__ fpk,
    const unsigned short* __restrict__ gpk,
    const unsigned short* __restrict__ vpkT,
    const float* __restrict__ Wv, const float* __restrict__ bv,
    const float* __restrict__ gamma,
    const float* __restrict__ x, float* __restrict__ out)
{
    __shared__ __align__(16) unsigned short glds[WAVES][MBLK][LROW]; // 20.0 KB
    __shared__ __align__(16) unsigned short vlds[WAVES][NH][LROW];   // 30.0 KB
    __shared__ __align__(16) unsigned short plds[WAVES][64][LROW];   // 40.0 KB
    __shared__ float so[64][HF + 2];                                 // 8.5 KB

    int tid  = threadIdx.x;
    int wave = tid >> 6;
    int lane = tid & 63;
    int c15  = lane & 15;
    int g4   = lane >> 4;
    int b  = blockIdx.x >> 6;
    int n0 = (blockIdx.x & 63) * 64;

    for (int i = tid; i < 64*(HF+2); i += THREADS) ((float*)so)[i] = 0.f;
    __syncthreads();

    // Q A-fragments: row = lane&15 (q = qg*16+c15), k-group g4: {fh,fl,fh,fl}
    bf16x8 aq[4];
    #pragma unroll
    for (int qg = 0; qg < 4; qg++) {
        const unsigned short* fp =
            fpk + ((size_t)(b * NN + n0 + qg*16 + c15)) * 16 + (g4 & 1) * 8;
        aq[qg] = *(const bf16x8*)fp;
    }

    f32x4 zero4 = {0.f, 0.f, 0.f, 0.f};
    f32x4 acc[4][3];
    #pragma unroll
    for (int qg = 0; qg < 4; qg++)
        #pragma unroll
        for (int hg = 0; hg < 3; hg++) acc[qg][hg] = zero4;

    unsigned short* gw = &glds[wave][0][0];
    unsigned short* vw = &vlds[wave][0][0];
    unsigned short* pw = &plds[wave][0][0];

    int mbase = wave * MCHUNK;
    int l2   = lane >> 2;     // 0..15: staged row
    int part = lane & 3;      // 16-B chunk within 64-B row

    const unsigned short* gsrc0 = gpk + (size_t)b * NN * 32 + part * 8;
    const unsigned short* vsrc0 = vpkT + (size_t)b * NH * NN + part * 8;

    uint4 sgr0, sgr1, svr0, svr1, svr2;

    // prologue: stage block 0
    {
        int m0 = mbase;
        sgr0 = *(const uint4*)(gsrc0 + (size_t)(m0 + l2)      * 32);
        sgr1 = *(const uint4*)(gsrc0 + (size_t)(m0 + l2 + 16) * 32);
        svr0 = *(const uint4*)(vsrc0 + (size_t)(l2)      * NN + m0);
        svr1 = *(const uint4*)(vsrc0 + (size_t)(l2 + 16) * NN + m0);
        svr2 = *(const uint4*)(vsrc0 + (size_t)(l2 + 32) * NN + m0);
        *(uint4*)(gw + (l2)      * LROW + part * 8) = sgr0;
        *(uint4*)(gw + (l2 + 16) * LROW + part * 8) = sgr1;
        *(uint4*)(vw + (l2)      * LROW + part * 8) = svr0;
        *(uint4*)(vw + (l2 + 16) * LROW + part * 8) = svr1;
        *(uint4*)(vw + (l2 + 32) * LROW + part * 8) = svr2;
    }

    for (int t = 0; t < NBLK; t++) {
        // T14: issue next block's global loads before compute
        if (t + 1 < NBLK) {
            int m1 = mbase + (t + 1) * MBLK;
            sgr0 = *(const uint4*)(gsrc0 + (size_t)(m1 + l2)      * 32);
            sgr1 = *(const uint4*)(gsrc0 + (size_t)(m1 + l2 + 16) * 32);
            svr0 = *(const uint4*)(vsrc0 + (size_t)(l2)      * NN + m1);
            svr1 = *(const uint4*)(vsrc0 + (size_t)(l2 + 16) * NN + m1);
            svr2 = *(const uint4*)(vsrc0 + (size_t)(l2 + 32) * NN + m1);
        }

        // QK^T: S[64 q][32 m], exact via hi/lo K-packing
        f32x4 sf[4][2];
        #pragma unroll
        for (int mg = 0; mg < 2; mg++) {
            bf16x8 bk = *(const bf16x8*)(gw + (mg*16 + c15) * LROW + g4 * 8);
            #pragma unroll
            for (int qg = 0; qg < 4; qg++)
                sf[qg][mg] = __builtin_amdgcn_mfma_f32_16x16x32_bf16(
                    aq[qg], bk, zero4, 0, 0, 0);
        }

        // exp (no max shift: |s| <~ 12, f32-safe), pack pairs (m, m+16) -> P
        #pragma unroll
        for (int qg = 0; qg < 4; qg++) {
            #pragma unroll
            for (int r = 0; r < 4; r++) {
                float e0 = __expf(sf[qg][0][r]);
                float e1 = __expf(sf[qg][1][r]);
                unsigned int pk = (unsigned int)f2bf(e0)
                                | ((unsigned int)f2bf(e1) << 16);
                int q = qg*16 + g4*4 + r;        // C-layout row
                *(unsigned int*)(pw + q * LROW + c15 * 2) = pk;
            }
        }
        asm volatile("s_waitcnt lgkmcnt(0)" ::: "memory"); // P visible wave-wide

        // P * V' (V' column coding matches P coding; row 32 of V' = ones -> L)
        bf16x8 vb[3];
        #pragma unroll
        for (int hg = 0; hg < 3; hg++)
            vb[hg] = *(const bf16x8*)(vw + (hg*16 + c15) * LROW + g4 * 8);
        #pragma unroll
        for (int qg = 0; qg < 4; qg++) {
            bf16x8 pa = *(const bf16x8*)(pw + (qg*16 + c15) * LROW + g4 * 8);
            #pragma unroll
            for (int hg = 0; hg < 3; hg++)
                acc[qg][hg] = __builtin_amdgcn_mfma_f32_16x16x32_bf16(
                    pa, vb[hg], acc[qg][hg], 0, 0, 0);
        }

        // write next block's staged tiles (reads above already processed:
        // per-wave DS pipe is in-order)
        if (t + 1 < NBLK) {
            *(uint4*)(gw + (l2)      * LROW + part * 8) = sgr0;
            *(uint4*)(gw + (l2 + 16) * LROW + part * 8) = sgr1;
            *(uint4*)(vw + (l2)      * LROW + part * 8) = svr0;
            *(uint4*)(vw + (l2 + 16) * LROW + part * 8) = svr1;
            *(uint4*)(vw + (l2 + 32) * LROW + part * 8) = svr2;
        }
    }

    // combine wave partials (no max shift -> plain sums)
    #pragma unroll
    for (int qg = 0; qg < 4; qg++)
        #pragma unroll
        for (int hg = 0; hg < 2; hg++)
            #pragma unroll
            for (int r = 0; r < 4; r++)
                atomicAdd(&so[qg*16 + g4*4 + r][hg*16 + c15], acc[qg][hg][r]);
    if (c15 == 0) {
        #pragma unroll
        for (int qg = 0; qg < 4; qg++)
            #pragma unroll
            for (int r = 0; r < 4; r++)
                atomicAdd(&so[qg*16 + g4*4 + r][HF], acc[qg][2][r]);
    }
    __syncthreads();

    // epilogue: normalize, Wv projection, gamma scale, residual
    int q  = tid & 63;
    int cb = tid >> 6;
    float rL = 1.f / so[q][HF];
    float o_[HF];
    #pragma unroll
    for (int h = 0; h < HF; h++) o_[h] = so[q][h] * rL;
    float gm = gamma[0];
    size_t obase = (size_t)b * CC * NN + n0 + q;
    for (int c = cb*8; c < cb*8 + 8; c++) {
        float v = bv[c];
        #pragma unroll
        for (int h = 0; h < HF; h++) v += Wv[c*HF + h] * o_[h];
        size_t a = obase + (size_t)c * NN;
        out[a] = gm * v + x[a];
    }
}

extern "C" void kernel_launch(void* const* d_in, const int* in_sizes, int n_in,
                              void* d_out, int out_size, void* d_ws, size_t ws_size,
                              hipStream_t stream) {
    const float* x     = (const float*)d_in[0];
    const float* Wf    = (const float*)d_in[1];
    const float* bf    = (const float*)d_in[2];
    const float* Wg    = (const float*)d_in[3];
    const float* bg    = (const float*)d_in[4];
    const float* Wh    = (const float*)d_in[5];
    const float* bh    = (const float*)d_in[6];
    const float* Wv    = (const float*)d_in[7];
    const float* bv    = (const float*)d_in[8];
    const float* gamma = (const float*)d_in[9];
    float* out = (float*)d_out;

    unsigned short* ws   = (unsigned short*)d_ws;
    unsigned short* fpk  = ws;                               // 4*4096*16
    unsigned short* gpk  = ws + (size_t)BB*NN*16;            // 4*4096*32
    unsigned short* vpkT = ws + (size_t)BB*NN*(16+32);       // 4*48*4096
    // total = 3,145,728 B (same footprint as previous rounds)

    proj_kernel<<<(BB*NN)/64, 64, 0, stream>>>(x, Wf, bf, Wg, bg, Wh, bh,
                                               fpk, gpk, vpkT);
    attn_kernel<<<BB*(NN/64), THREADS, 0, stream>>>(fpk, gpk, vpkT,
                                                    Wv, bv, gamma, x, out);
}

// Round 6
// 67.640 us; speedup vs baseline: 3.6442x; 1.0190x over previous
//
#include <hip/hip_runtime.h>
#include <math.h>

#define BB 4
#define CC 64
#define NN 4096
#define IND 8
#define HF 32
#define THREADS 512
#define WAVES 8
#define MBLK 32
#define MCHUNK (NN/WAVES)    // 512 m's per wave
#define NBLK (MCHUNK/MBLK)   // 16 blocks

typedef __attribute__((ext_vector_type(8))) short bf16x8;
typedef __attribute__((ext_vector_type(4))) float f32x4;

static __device__ __forceinline__ unsigned short f2bf(float x) {
    unsigned int u = __float_as_uint(x);
    u = (u + 0x7FFFu + ((u >> 16) & 1u)) >> 16;   // RNE
    return (unsigned short)u;
}
static __device__ __forceinline__ float bf2f(unsigned short h) {
    return __uint_as_float(((unsigned int)h) << 16);
}
static __device__ __forceinline__ unsigned int pk2(float lo, float hi) {
    return (unsigned int)f2bf(lo) | ((unsigned int)f2bf(hi) << 16);
}
static __device__ __forceinline__ float ex2(float x) {
    return __builtin_amdgcn_exp2f(x);   // v_exp_f32 (2^x)
}

// m -> k-slot coding shared by P (in-register) and V (pre-permuted columns):
// k(m5) = (m5&3) | ((m5>>4)&1)<<2 | ((m5>>2)&3)<<3   (bijective on 0..31)

// Kernel 1: 1x1-conv projections -> packed bf16 workspaces.
// fpk [B][N][16]: [fh(8), fl(8)]            (Q hi/lo split; B-operand octets via g4&1)
// gpk [B][N][32]: [gh, gh, gl, gl]          (K hi/lo packed; log2e pre-folded)
// vpkT[B][32][N]: row h, column (m&~31)|k(m&31) holds bf16(hv[h][m])
__global__ __launch_bounds__(64) void proj_kernel(
    const float* __restrict__ x,
    const float* __restrict__ Wf, const float* __restrict__ bf,
    const float* __restrict__ Wg, const float* __restrict__ bg,
    const float* __restrict__ Wh, const float* __restrict__ bh,
    unsigned short* __restrict__ fpk,
    unsigned short* __restrict__ gpk,
    unsigned short* __restrict__ vpkT)
{
    int tid = threadIdx.x;
    int idx = blockIdx.x * 64 + tid;
    int b = idx >> 12;
    int n = idx & (NN - 1);
    const float* xp = x + (size_t)b * CC * NN + n;

    // hoist all x loads (lets the scheduler keep many in flight)
    float xv[CC];
    #pragma unroll
    for (int c = 0; c < CC; c++) xv[c] = xp[(size_t)c * NN];

    float fa[IND], ga[IND], ha[HF];
    #pragma unroll
    for (int o = 0; o < IND; o++) { fa[o] = bf[o]; ga[o] = bg[o]; }
    #pragma unroll
    for (int h = 0; h < HF; h++) ha[h] = bh[h];

    #pragma unroll
    for (int c = 0; c < CC; c++) {
        float v = xv[c];
        #pragma unroll
        for (int o = 0; o < IND; o++) {
            fa[o] += Wf[o*CC + c] * v;   // wave-uniform W -> s_load
            ga[o] += Wg[o*CC + c] * v;
        }
        #pragma unroll
        for (int h = 0; h < HF; h++) ha[h] += Wh[h*CC + c] * v;
    }

    const float LOG2E = 1.4426950408889634f;
    size_t base = (size_t)b * NN + n;

    union { unsigned short s[16]; uint4 q[2]; } fo;
    #pragma unroll
    for (int o = 0; o < IND; o++) {
        unsigned short hi = f2bf(fa[o]);
        unsigned short lo = f2bf(fa[o] - bf2f(hi));
        fo.s[o] = hi; fo.s[8 + o] = lo;
    }
    uint4* fdst = (uint4*)(fpk + base * 16);
    fdst[0] = fo.q[0]; fdst[1] = fo.q[1];

    union { unsigned short s[32]; uint4 q[4]; } go;
    #pragma unroll
    for (int o = 0; o < IND; o++) {
        float gsc = ga[o] * LOG2E;                 // exp -> exp2 fold
        unsigned short hi = f2bf(gsc);
        unsigned short lo = f2bf(gsc - bf2f(hi));
        go.s[o] = hi; go.s[8 + o] = hi; go.s[16 + o] = lo; go.s[24 + o] = lo;
    }
    uint4* gdst = (uint4*)(gpk + base * 32);
    #pragma unroll
    for (int k = 0; k < 4; k++) gdst[k] = go.q[k];

    int m5 = n & 31;
    int code = (m5 & 3) | (((m5 >> 4) & 1) << 2) | (((m5 >> 2) & 3) << 3);
    int pos = (n & ~31) | code;
    unsigned short* vp = vpkT + (size_t)b * HF * NN + pos;
    #pragma unroll
    for (int h = 0; h < HF; h++) vp[(size_t)h * NN] = f2bf(ha[h]);
}

// Kernel 2: register-only MFMA flash attention + fused Wv/gamma/residual.
// 256 WGs = B * (N/64); 8 waves, each owns all 64 q's and a 512-m strip.
// Swapped QK (mfma(K,Q)) => S lands as the PV A-fragment: no LDS in main loop.
__global__ __launch_bounds__(THREADS) void attn_kernel(
    const unsigned short* __restrict__ fpk,
    const unsigned short* __restrict__ gpk,
    const unsigned short* __restrict__ vpkT,
    const float* __restrict__ Wv, const float* __restrict__ bv,
    const float* __restrict__ gamma,
    const float* __restrict__ x, float* __restrict__ out)
{
    __shared__ float so[64][HF + 2];

    int tid  = threadIdx.x;
    int wave = tid >> 6;
    int lane = tid & 63;
    int c15  = lane & 15;
    int g4   = lane >> 4;
    int b  = blockIdx.x >> 6;
    int n0 = (blockIdx.x & 63) * 64;

    for (int i = tid; i < 64*(HF+2); i += THREADS) ((float*)so)[i] = 0.f;
    __syncthreads();

    // Q as B-operand: col=c15 -> q = n0+qg*16+c15, k-octet g4 -> [fh,fl,fh,fl]
    bf16x8 bq[4];
    #pragma unroll
    for (int qg = 0; qg < 4; qg++)
        bq[qg] = *(const bf16x8*)(fpk
                  + ((size_t)(b * NN + n0 + qg*16 + c15)) * 16 + (g4 & 1) * 8);

    f32x4 zero4 = {0.f, 0.f, 0.f, 0.f};
    f32x4 acc[4][2];
    float Lacc[4] = {0.f, 0.f, 0.f, 0.f};
    #pragma unroll
    for (int qg = 0; qg < 4; qg++) { acc[qg][0] = zero4; acc[qg][1] = zero4; }

    const unsigned short* gsrc = gpk  + (size_t)b * NN * 32;
    const unsigned short* vsrc = vpkT + (size_t)b * HF * NN;
    int mbase = wave * MCHUNK;

    // K A-fragment: row=c15 -> m = m0+mg*16+c15, octet g4
    // V B-fragment: col=c15 -> h = hg*16+c15, k-octet g4 -> cols m0+g4*8..+7
    bf16x8 akc[2], vbc[2], akn[2], vbn[2];
    {
        int m0 = mbase;
        akc[0] = *(const bf16x8*)(gsrc + (size_t)(m0 + c15)      * 32 + g4*8);
        akc[1] = *(const bf16x8*)(gsrc + (size_t)(m0 + 16 + c15) * 32 + g4*8);
        vbc[0] = *(const bf16x8*)(vsrc + (size_t)(c15)      * NN + m0 + g4*8);
        vbc[1] = *(const bf16x8*)(vsrc + (size_t)(16 + c15) * NN + m0 + g4*8);
    }

    #pragma unroll
    for (int t = 0; t < NBLK; t++) {
        if (t + 1 < NBLK) {
            int m1 = mbase + (t + 1) * MBLK;
            akn[0] = *(const bf16x8*)(gsrc + (size_t)(m1 + c15)      * 32 + g4*8);
            akn[1] = *(const bf16x8*)(gsrc + (size_t)(m1 + 16 + c15) * 32 + g4*8);
            vbn[0] = *(const bf16x8*)(vsrc + (size_t)(c15)      * NN + m1 + g4*8);
            vbn[1] = *(const bf16x8*)(vsrc + (size_t)(16 + c15) * NN + m1 + g4*8);
        }

        // swapped QK^T: D[m-row][q-col]; exact hi/lo product
        f32x4 sf[4][2];
        #pragma unroll
        for (int mg = 0; mg < 2; mg++)
            #pragma unroll
            for (int qg = 0; qg < 4; qg++)
                sf[qg][mg] = __builtin_amdgcn_mfma_f32_16x16x32_bf16(
                    akc[mg], bq[qg], zero4, 0, 0, 0);

        // exp2 (log2e pre-folded; no max shift: |S'| < ~25, f32-safe),
        // pack straight into the PV A-fragment (k = r + 4*mg + 8*g4)
        bf16x8 pa[4];
        #pragma unroll
        for (int qg = 0; qg < 4; qg++) {
            float e00 = ex2(sf[qg][0][0]), e01 = ex2(sf[qg][0][1]);
            float e02 = ex2(sf[qg][0][2]), e03 = ex2(sf[qg][0][3]);
            float e10 = ex2(sf[qg][1][0]), e11 = ex2(sf[qg][1][1]);
            float e12 = ex2(sf[qg][1][2]), e13 = ex2(sf[qg][1][3]);
            Lacc[qg] += ((e00 + e01) + (e02 + e03)) + ((e10 + e11) + (e12 + e13));
            union { unsigned int u[4]; bf16x8 v; } p;
            p.u[0] = pk2(e00, e01); p.u[1] = pk2(e02, e03);
            p.u[2] = pk2(e10, e11); p.u[3] = pk2(e12, e13);
            pa[qg] = p.v;
        }

        // P * V: acc[qg][hg], D: col=c15=h, row=g4*4+r=q
        #pragma unroll
        for (int qg = 0; qg < 4; qg++)
            #pragma unroll
            for (int hg = 0; hg < 2; hg++)
                acc[qg][hg] = __builtin_amdgcn_mfma_f32_16x16x32_bf16(
                    pa[qg], vbc[hg], acc[qg][hg], 0, 0, 0);

        akc[0] = akn[0]; akc[1] = akn[1];
        vbc[0] = vbn[0]; vbc[1] = vbn[1];
    }

    // combine wave partials (waves arrive desynced -> low atomic contention)
    #pragma unroll
    for (int qg = 0; qg < 4; qg++)
        #pragma unroll
        for (int hg = 0; hg < 2; hg++)
            #pragma unroll
            for (int r = 0; r < 4; r++)
                atomicAdd(&so[qg*16 + g4*4 + r][hg*16 + c15], acc[qg][hg][r]);
    #pragma unroll
    for (int qg = 0; qg < 4; qg++)
        atomicAdd(&so[qg*16 + c15][HF], Lacc[qg]);
    __syncthreads();

    // epilogue: normalize, Wv projection, gamma, residual
    int q  = tid & 63;
    int cb = tid >> 6;
    float rL = 1.f / so[q][HF];
    float o_[HF];
    #pragma unroll
    for (int h = 0; h < HF; h++) o_[h] = so[q][h] * rL;
    float gm = gamma[0];
    size_t obase = (size_t)b * CC * NN + n0 + q;
    for (int c = cb*8; c < cb*8 + 8; c++) {
        float v = bv[c];
        #pragma unroll
        for (int h = 0; h < HF; h++) v += Wv[c*HF + h] * o_[h];
        size_t a = obase + (size_t)c * NN;
        out[a] = gm * v + x[a];
    }
}

extern "C" void kernel_launch(void* const* d_in, const int* in_sizes, int n_in,
                              void* d_out, int out_size, void* d_ws, size_t ws_size,
                              hipStream_t stream) {
    const float* x     = (const float*)d_in[0];
    const float* Wf    = (const float*)d_in[1];
    const float* bf    = (const float*)d_in[2];
    const float* Wg    = (const float*)d_in[3];
    const float* bg    = (const float*)d_in[4];
    const float* Wh    = (const float*)d_in[5];
    const float* bh    = (const float*)d_in[6];
    const float* Wv    = (const float*)d_in[7];
    const float* bv    = (const float*)d_in[8];
    const float* gamma = (const float*)d_in[9];
    float* out = (float*)d_out;

    unsigned short* ws   = (unsigned short*)d_ws;
    unsigned short* fpk  = ws;                               // B*N*16
    unsigned short* gpk  = ws + (size_t)BB*NN*16;            // B*N*32
    unsigned short* vpkT = ws + (size_t)BB*NN*48;            // B*32*N
    // total 2.62 MB

    proj_kernel<<<(BB*NN)/64, 64, 0, stream>>>(x, Wf, bf, Wg, bg, Wh, bh,
                                               fpk, gpk, vpkT);
    attn_kernel<<<BB*(NN/64), THREADS, 0, stream>>>(fpk, gpk, vpkT,
                                                    Wv, bv, gamma, x, out);
}